// Round 2
// baseline (472.283 us; speedup 1.0000x reference)
//
#include <hip/hip_runtime.h>

#define N_ROWS 32768
#define DIM 256
#define K_CODES 1024
#define OUT_QUANT 8388608  // N_ROWS*DIM; out layout: [quant | loss | encodings]

typedef unsigned long long ull;
typedef __attribute__((ext_vector_type(8))) short bf16x8;
typedef __attribute__((ext_vector_type(4))) float f32x4;

// ---------- exact numpy pairwise sum-of-squares over 128 contiguous floats ----------
__device__ __forceinline__ float pw128sq(const float* __restrict__ x) {
  float r[8];
#pragma unroll
  for (int j = 0; j < 8; ++j) r[j] = __fmul_rn(x[j], x[j]);
#pragma unroll
  for (int i = 8; i < 128; i += 8) {
#pragma unroll
    for (int j = 0; j < 8; ++j) r[j] = __fadd_rn(r[j], __fmul_rn(x[i + j], x[i + j]));
  }
  return __fadd_rn(__fadd_rn(__fadd_rn(r[0], r[1]), __fadd_rn(r[2], r[3])),
                   __fadd_rn(__fadd_rn(r[4], r[5]), __fadd_rn(r[6], r[7])));
}

__global__ __launch_bounds__(256) void row_norms(const float* __restrict__ z,
                                                 float* __restrict__ rn) {
  int r = blockIdx.x * 256 + threadIdx.x;
  if (r < N_ROWS)
    rn[r] = __fadd_rn(pw128sq(z + (size_t)r * DIM), pw128sq(z + (size_t)r * DIM + 128));
}

__global__ __launch_bounds__(256) void code_norms(const float* __restrict__ cb,
                                                  float* __restrict__ cn) {
  int k = blockIdx.x * 256 + threadIdx.x;
  if (k < K_CODES)
    cn[k] = __fadd_rn(pw128sq(cb + (size_t)k * DIM), pw128sq(cb + (size_t)k * DIM + 128));
}

// ---------- exact truncation split fp32 -> bf16 hi/mid/lo ----------
__device__ __forceinline__ void split3(float x, unsigned short& h, unsigned short& m,
                                       unsigned short& l) {
  unsigned int u = __float_as_uint(x);
  unsigned int hb = u & 0xFFFF0000u;
  h = (unsigned short)(hb >> 16);
  float r1 = __fsub_rn(x, __uint_as_float(hb));          // exact
  unsigned int mb = __float_as_uint(r1) & 0xFFFF0000u;
  m = (unsigned short)(mb >> 16);
  float r2 = __fsub_rn(r1, __uint_as_float(mb));         // exact
  // round-to-nearest bf16 of r2
  unsigned int u2 = __float_as_uint(r2);
  unsigned int rounded = u2 + 0x7FFFu + ((u2 >> 16) & 1u);
  l = (unsigned short)(rounded >> 16);
}

__global__ __launch_bounds__(256) void split_z(const float* __restrict__ z,
                                               unsigned short* __restrict__ zh,
                                               unsigned short* __restrict__ zm,
                                               unsigned short* __restrict__ zl) {
  const size_t i = ((size_t)blockIdx.x * 256 + threadIdx.x) * 4;
  const float4 v = *(const float4*)(z + i);
  ushort4 h, m, l;
  split3(v.x, h.x, m.x, l.x);
  split3(v.y, h.y, m.y, l.y);
  split3(v.z, h.z, m.z, l.z);
  split3(v.w, h.w, m.w, l.w);
  *(ushort4*)(zh + i) = h;
  *(ushort4*)(zm + i) = m;
  *(ushort4*)(zl + i) = l;
}

// ---------- MFMA GEMM (6-term bf16 split dot) + fused distance argmin ----------
// block: 256 threads (4 waves), tile 128x128, wave tile 64x64, BK=32
__device__ __forceinline__ void lds16(const void* g, void* l) {
  __builtin_amdgcn_global_load_lds(
      (const __attribute__((address_space(1))) unsigned int*)g,
      (__attribute__((address_space(3))) unsigned int*)l, 16, 0, 0);
}

__device__ __forceinline__ ull shflx64(ull v, int m) {
  int lo = __shfl_xor((int)(v & 0xffffffffull), m);
  int hi = __shfl_xor((int)(v >> 32), m);
  return ((ull)(unsigned int)hi << 32) | (unsigned int)lo;
}

__global__ __launch_bounds__(256) void gemm_argmin_mfma(
    const unsigned short* __restrict__ zh, const unsigned short* __restrict__ zm,
    const unsigned short* __restrict__ zl, const unsigned short* __restrict__ ch,
    const unsigned short* __restrict__ cm, const unsigned short* __restrict__ cl,
    const float* __restrict__ rn, const float* __restrict__ cn,
    ull* __restrict__ keys) {
  __shared__ unsigned short As[4 * 128 * 8];  // [kg][row][8] bf16, 8KB
  __shared__ unsigned short Bs[4 * 128 * 8];

  // XCD-aware mapping: 8 col-blocks of one row-panel on the same XCD
  const int bid = blockIdx.x;
  const int xcd = bid & 7;
  const int i = bid >> 3;
  const int bm = xcd * 32 + (i >> 3);
  const int bn = i & 7;
  const int row0 = bm * 128, col0 = bn * 128;

  const int tid = threadIdx.x;
  const int wid = tid >> 6, lane = tid & 63;
  const int wm = wid >> 1, wn = wid & 1;
  const int lq = lane >> 4, lr = lane & 15;
  const int srow = tid & 127, shalf = tid >> 7;  // staging: row, k-half

  f32x4 acc[4][4];
#pragma unroll
  for (int a = 0; a < 4; ++a)
#pragma unroll
    for (int b = 0; b < 4; ++b) acc[a][b] = (f32x4){0.f, 0.f, 0.f, 0.f};

  const unsigned short* As_g_row = nullptr;  // silence unused warnings

  auto kpass = [&](const unsigned short* __restrict__ Ag,
                   const unsigned short* __restrict__ Bg) {
    for (int kk = 0; kk < DIM; kk += 32) {
      __syncthreads();  // previous iteration's ds_reads complete
#pragma unroll
      for (int is = 0; is < 2; ++is) {
        lds16(Ag + (size_t)(row0 + srow) * DIM + kk + is * 16 + shalf * 8,
              (char*)As + is * 4096 + tid * 16);
        lds16(Bg + (size_t)(col0 + srow) * DIM + kk + is * 16 + shalf * 8,
              (char*)Bs + is * 4096 + tid * 16);
      }
      __syncthreads();  // drains vmcnt(0)

      bf16x8 av[4], bv[4];
      const bf16x8* As8 = (const bf16x8*)As;
      const bf16x8* Bs8 = (const bf16x8*)Bs;
#pragma unroll
      for (int fm = 0; fm < 4; ++fm) av[fm] = As8[lq * 128 + wm * 64 + fm * 16 + lr];
#pragma unroll
      for (int fn = 0; fn < 4; ++fn) bv[fn] = Bs8[lq * 128 + wn * 64 + fn * 16 + lr];
#pragma unroll
      for (int fm = 0; fm < 4; ++fm)
#pragma unroll
        for (int fn = 0; fn < 4; ++fn)
          acc[fm][fn] = __builtin_amdgcn_mfma_f32_16x16x32_bf16(av[fm], bv[fn],
                                                                acc[fm][fn], 0, 0, 0);
    }
  };

  // 6 kept terms of the (h+m+l)x(h+m+l) expansion (>= 2^-21 relative)
  kpass(zh, ch);
  kpass(zh, cm);
  kpass(zm, ch);
  kpass(zh, cl);
  kpass(zl, ch);
  kpass(zm, cm);
  (void)As_g_row;

  // epilogue: dist = fp32((rn + cn) - 2*dot); argmin, first-index tie-break
  float cnv[4];
#pragma unroll
  for (int fn = 0; fn < 4; ++fn) cnv[fn] = cn[col0 + wn * 64 + fn * 16 + lr];

#pragma unroll
  for (int fm = 0; fm < 4; ++fm) {
#pragma unroll
    for (int j = 0; j < 4; ++j) {
      const int rg = row0 + wm * 64 + fm * 16 + lq * 4 + j;
      const float a_rn = rn[rg];
      ull best = ~0ull;
#pragma unroll
      for (int fn = 0; fn < 4; ++fn) {
        const int cg = col0 + wn * 64 + fn * 16 + lr;
        const float d = __fsub_rn(__fadd_rn(a_rn, cnv[fn]), 2.0f * acc[fm][fn][j]);
        unsigned int b = __float_as_uint(d);
        b = (b & 0x80000000u) ? ~b : (b | 0x80000000u);
        const ull key = ((ull)b << 32) | (unsigned int)cg;
        if (key < best) best = key;
      }
#pragma unroll
      for (int off = 1; off <= 8; off <<= 1) {
        ull o = shflx64(best, off);
        if (o < best) best = o;
      }
      if (lr == 0) atomicMin(&keys[rg], best);
    }
  }
}

// ---------- outputs: quantized, full one-hot rows, loss partials ----------
__global__ __launch_bounds__(256) void quantize_out(
    const float* __restrict__ z, const float* __restrict__ cb,
    const ull* __restrict__ keys, float* __restrict__ out,
    float* __restrict__ lossp) {
  __shared__ float ls[4];
  const int wid = threadIdx.x >> 6, lane = threadIdx.x & 63;
  const int row = blockIdx.x * 4 + wid;
  const int idx = (int)(keys[row] & 0xffffffffull);
  const float4 zv = *(const float4*)(z + (size_t)row * DIM + lane * 4);
  const float4 qv = *(const float4*)(cb + (size_t)idx * DIM + lane * 4);
  const float dx = __fsub_rn(qv.x, zv.x);
  const float dy = __fsub_rn(qv.y, zv.y);
  const float dzz = __fsub_rn(qv.z, zv.z);
  const float dw = __fsub_rn(qv.w, zv.w);
  float4 ov;
  ov.x = __fadd_rn(zv.x, dx); ov.y = __fadd_rn(zv.y, dy);
  ov.z = __fadd_rn(zv.z, dzz); ov.w = __fadd_rn(zv.w, dw);
  *(float4*)(out + (size_t)row * DIM + lane * 4) = ov;
  float s = dx * dx + dy * dy + dzz * dzz + dw * dw;
#pragma unroll
  for (int o = 32; o > 0; o >>= 1) s += __shfl_down(s, o);
  if (lane == 0) ls[wid] = s;

  // full one-hot row (replaces giant memset)
  float4* enc4 = (float4*)(out + (size_t)OUT_QUANT + 1 + (size_t)row * K_CODES);
  const int target = idx >> 2, comp = idx & 3;
#pragma unroll
  for (int i = 0; i < 4; ++i) {
    const int f4i = lane + 64 * i;
    float4 v = {0.f, 0.f, 0.f, 0.f};
    if (f4i == target) ((float*)&v)[comp] = 1.0f;
    enc4[f4i] = v;
  }

  __syncthreads();
  if (threadIdx.x == 0) lossp[blockIdx.x] = ls[0] + ls[1] + ls[2] + ls[3];
}

__global__ __launch_bounds__(256) void loss_final(const float* __restrict__ lossp,
                                                  float* __restrict__ out) {
  __shared__ float sm[256];
  float v = 0.f;
  for (int i = threadIdx.x; i < 8192; i += 256) v += lossp[i];
  sm[threadIdx.x] = v;
  __syncthreads();
  for (int s = 128; s > 0; s >>= 1) {
    if (threadIdx.x < s) sm[threadIdx.x] += sm[threadIdx.x + s];
    __syncthreads();
  }
  if (threadIdx.x == 0) out[OUT_QUANT] = sm[0] * (1.25f / 8388608.0f);
}

extern "C" void kernel_launch(void* const* d_in, const int* in_sizes, int n_in,
                              void* d_out, int out_size, void* d_ws, size_t ws_size,
                              hipStream_t stream) {
  const float* z = (const float*)d_in[0];
  const float* cb = (const float*)d_in[1];
  float* out = (float*)d_out;

  // ws layout (bytes): keys u64[32768] @0 | rn @256K | cn @384K | lossp @388K |
  //                    zh @1M | zm @17M | zl @33M | ch @49M | cm @49.5M | cl @50M
  char* w = (char*)d_ws;
  ull* keys = (ull*)w;
  float* rn = (float*)(w + (256u << 10));
  float* cn = (float*)(w + (384u << 10));
  float* lossp = (float*)(w + (388u << 10));
  unsigned short* zh = (unsigned short*)(w + (1u << 20));
  unsigned short* zm = (unsigned short*)(w + (17u << 20));
  unsigned short* zl = (unsigned short*)(w + (33u << 20));
  unsigned short* ch = (unsigned short*)(w + (49u << 20));
  unsigned short* cm = (unsigned short*)(w + (49u << 20) + (512u << 10));
  unsigned short* cl = (unsigned short*)(w + (50u << 20));

  hipMemsetAsync(keys, 0xFF, (size_t)N_ROWS * 8, stream);

  row_norms<<<N_ROWS / 256, 256, 0, stream>>>(z, rn);
  code_norms<<<K_CODES / 256, 256, 0, stream>>>(cb, cn);
  split_z<<<(N_ROWS * DIM) / 1024, 256, 0, stream>>>(z, zh, zm, zl);
  split_z<<<(K_CODES * DIM) / 1024, 256, 0, stream>>>(cb, ch, cm, cl);
  gemm_argmin_mfma<<<2048, 256, 0, stream>>>(zh, zm, zl, ch, cm, cl, rn, cn, keys);
  quantize_out<<<N_ROWS / 4, 256, 0, stream>>>(z, cb, keys, out, lossp);
  loss_final<<<1, 256, 0, stream>>>(lossp, out);
}

// Round 4
// 439.230 us; speedup vs baseline: 1.0753x; 1.0753x over previous
//
#include <hip/hip_runtime.h>

#define N_ROWS 32768
#define DIM 256
#define K_CODES 1024
#define KTOT 768
#define OUT_QUANT 8388608  // N_ROWS*DIM; out layout: [quant | loss | encodings]

typedef unsigned long long ull;
typedef _Float16 f16;
typedef __attribute__((ext_vector_type(4))) _Float16 f16x4;
typedef __attribute__((ext_vector_type(8))) _Float16 f16x8;
typedef __attribute__((ext_vector_type(4))) float f32x4;

#define NB_ZSPLIT 8192
#define NB_ZNORM 2048
#define NB_CSPLIT 256
#define NB_CNORM 64

// ---- fp16 2-way split: h = fp16(x) (self-flushed below 2^-14), l = fp16((x-h)*2^12)
struct HL { f16 h, l; };
__device__ __forceinline__ HL split2(float x) {
  f16 hh = (f16)x;
  if (__builtin_fabsf(x) < 6.103515625e-05f) hh = (f16)0.0f;
  const float r = __fsub_rn(x, (float)hh);  // exact (Sterbenz / bit-subset)
  HL o;
  o.h = hh;
  o.l = (f16)(__fmul_rn(r, 4096.0f));
  return o;
}

// ---- one prep kernel: z-split, z-norms(+keys init), cb-split(+loss zero), cb-norms ----
__global__ __launch_bounds__(256) void prep(
    const float* __restrict__ z, const float* __restrict__ cb,
    f16* __restrict__ Ap, f16* __restrict__ Bp,
    float* __restrict__ rn, float* __restrict__ cn,
    ull* __restrict__ keys, float* __restrict__ out) {
  const int b = blockIdx.x, tid = threadIdx.x;
  if (b < NB_ZSPLIT) {
    // A' row = [h_z(256) | l_z(256) | h_z(256)]
    const size_t g = ((size_t)b * 256 + tid) * 4;
    const int row = (int)(g >> 8), k = (int)(g & 255);
    const float4 v = *(const float4*)(z + g);
    const HL s0 = split2(v.x), s1 = split2(v.y), s2 = split2(v.z), s3 = split2(v.w);
    const f16x4 h = {s0.h, s1.h, s2.h, s3.h};
    const f16x4 l = {s0.l, s1.l, s2.l, s3.l};
    f16* arow = Ap + (size_t)row * KTOT + k;
    *(f16x4*)(arow) = h;
    *(f16x4*)(arow + 256) = l;
    *(f16x4*)(arow + 512) = h;
  } else if (b < NB_ZSPLIT + NB_ZNORM) {
    // exact numpy pairwise ||z_row||^2: 8 chains/half, stride-8, tree combine
    const int row = (b - NB_ZSPLIT) * 16 + (tid >> 4);
    const int j = tid & 7, half = (tid >> 3) & 1;
    const float* x = z + (size_t)row * DIM + half * 128 + j;
    float r = __fmul_rn(x[0], x[0]);
#pragma unroll
    for (int t = 1; t < 16; ++t) r = __fadd_rn(r, __fmul_rn(x[8 * t], x[8 * t]));
    r = __fadd_rn(r, __shfl_xor(r, 1));
    r = __fadd_rn(r, __shfl_xor(r, 2));
    r = __fadd_rn(r, __shfl_xor(r, 4));
    const float o = __shfl_xor(r, 8);
    if ((tid & 15) == 0) {
      rn[row] = __fadd_rn(r, o);
      keys[row] = ~0ull;
    }
  } else if (b < NB_ZSPLIT + NB_ZNORM + NB_CSPLIT) {
    // B' row = [h_e(256) | h_e(256) | l_e(256)], e pre-scaled by 2^10
    const int b2 = b - (NB_ZSPLIT + NB_ZNORM);
    const size_t g = ((size_t)b2 * 256 + tid) * 4;
    const int row = (int)(g >> 8), k = (int)(g & 255);
    const float4 v = *(const float4*)(cb + g);
    const HL s0 = split2(__fmul_rn(v.x, 1024.0f));
    const HL s1 = split2(__fmul_rn(v.y, 1024.0f));
    const HL s2 = split2(__fmul_rn(v.z, 1024.0f));
    const HL s3 = split2(__fmul_rn(v.w, 1024.0f));
    const f16x4 h = {s0.h, s1.h, s2.h, s3.h};
    const f16x4 l = {s0.l, s1.l, s2.l, s3.l};
    f16* brow = Bp + (size_t)row * KTOT + k;
    *(f16x4*)(brow) = h;
    *(f16x4*)(brow + 256) = h;
    *(f16x4*)(brow + 512) = l;
    if (b2 == 0 && tid == 0) out[OUT_QUANT] = 0.0f;
  } else {
    const int row = (b - (NB_ZSPLIT + NB_ZNORM + NB_CSPLIT)) * 16 + (tid >> 4);
    const int j = tid & 7, half = (tid >> 3) & 1;
    const float* x = cb + (size_t)row * DIM + half * 128 + j;
    float r = __fmul_rn(x[0], x[0]);
#pragma unroll
    for (int t = 1; t < 16; ++t) r = __fadd_rn(r, __fmul_rn(x[8 * t], x[8 * t]));
    r = __fadd_rn(r, __shfl_xor(r, 1));
    r = __fadd_rn(r, __shfl_xor(r, 2));
    r = __fadd_rn(r, __shfl_xor(r, 4));
    const float o = __shfl_xor(r, 8);
    if ((tid & 15) == 0) cn[row] = __fadd_rn(r, o);
  }
}

// ---------- MFMA GEMM (fp16 split, K=768) + fused distance argmin ----------
__device__ __forceinline__ void lds16(const void* g, void* l) {
  __builtin_amdgcn_global_load_lds(
      (const __attribute__((address_space(1))) unsigned int*)g,
      (__attribute__((address_space(3))) unsigned int*)l, 16, 0, 0);
}

__device__ __forceinline__ ull shflx64(ull v, int m) {
  int lo = __shfl_xor((int)(v & 0xffffffffull), m);
  int hi = __shfl_xor((int)(v >> 32), m);
  return ((ull)(unsigned int)hi << 32) | (unsigned int)lo;
}

__global__ __launch_bounds__(256) void gemm_argmin_f16(
    const f16* __restrict__ Ap, const f16* __restrict__ Bp,
    const float* __restrict__ rn, const float* __restrict__ cn,
    ull* __restrict__ keys) {
  __shared__ f16 As[2][4096];  // 2 x 8KB, layout [kg(4)][row(128)][8]
  __shared__ f16 Bs[2][4096];

  const int bid = blockIdx.x;
  const int xcd = bid & 7, ii = bid >> 3;
  const int bm = xcd * 32 + (ii >> 3), bn = ii & 7;
  const int row0 = bm * 128, col0 = bn * 128;
  const int tid = threadIdx.x, wid = tid >> 6, lane = tid & 63;
  const int wm = wid >> 1, wn = wid & 1, lq = lane >> 4, lr = lane & 15;
  const int srow = tid & 127, shalf = tid >> 7;

  f32x4 acc[4][4];
#pragma unroll
  for (int a = 0; a < 4; ++a)
#pragma unroll
    for (int c = 0; c < 4; ++c) acc[a][c] = (f32x4){0.f, 0.f, 0.f, 0.f};

  const f16* aG = Ap + (size_t)(row0 + srow) * KTOT + shalf * 8;
  const f16* bG = Bp + (size_t)(col0 + srow) * KTOT + shalf * 8;

  // prologue: stage t=0 into buf 0
#pragma unroll
  for (int is = 0; is < 2; ++is) {
    lds16(aG + is * 16, (char*)As[0] + is * 4096 + tid * 16);
    lds16(bG + is * 16, (char*)Bs[0] + is * 4096 + tid * 16);
  }
  __syncthreads();

#pragma unroll
  for (int t = 0; t < 24; ++t) {
    const int cur = t & 1, nxt = cur ^ 1;
    if (t < 23) {  // issue next-tile staging before compute (2-phase overlap)
#pragma unroll
      for (int is = 0; is < 2; ++is) {
        lds16(aG + (t + 1) * 32 + is * 16, (char*)As[nxt] + is * 4096 + tid * 16);
        lds16(bG + (t + 1) * 32 + is * 16, (char*)Bs[nxt] + is * 4096 + tid * 16);
      }
    }
    if (t == 8) {  // chunk0 (h.h, scale 2^10) -> scale 2^22 before residual chunks
#pragma unroll
      for (int a = 0; a < 4; ++a)
#pragma unroll
        for (int c = 0; c < 4; ++c) acc[a][c] *= 4096.0f;
    }
    f16x8 av[4], bv[4];
    const f16x8* As8 = (const f16x8*)As[cur];
    const f16x8* Bs8 = (const f16x8*)Bs[cur];
#pragma unroll
    for (int fm = 0; fm < 4; ++fm) av[fm] = As8[lq * 128 + wm * 64 + fm * 16 + lr];
#pragma unroll
    for (int fn = 0; fn < 4; ++fn) bv[fn] = Bs8[lq * 128 + wn * 64 + fn * 16 + lr];
#pragma unroll
    for (int fm = 0; fm < 4; ++fm)
#pragma unroll
      for (int fn = 0; fn < 4; ++fn)
        acc[fm][fn] = __builtin_amdgcn_mfma_f32_16x16x32_f16(av[fm], bv[fn],
                                                             acc[fm][fn], 0, 0, 0);
    __syncthreads();  // drains vmcnt (next tile staged) + lgkm; single barrier/step
  }

  // epilogue: dist = fp32((rn+cn) - acc*2^-21); argmin, first-index ties
  float cnv[4];
#pragma unroll
  for (int fn = 0; fn < 4; ++fn) cnv[fn] = cn[col0 + wn * 64 + fn * 16 + lr];

#pragma unroll
  for (int fm = 0; fm < 4; ++fm) {
#pragma unroll
    for (int j = 0; j < 4; ++j) {
      const int rg = row0 + wm * 64 + fm * 16 + lq * 4 + j;
      const float a_rn = rn[rg];
      ull best = ~0ull;
#pragma unroll
      for (int fn = 0; fn < 4; ++fn) {
        const int cg = col0 + wn * 64 + fn * 16 + lr;
        const float d = __fsub_rn(__fadd_rn(a_rn, cnv[fn]),
                                  __fmul_rn(acc[fm][fn][j], 4.76837158203125e-07f));
        unsigned int mono = __float_as_uint(d);
        mono = (mono & 0x80000000u) ? ~mono : (mono | 0x80000000u);
        const ull key = ((ull)mono << 32) | (unsigned int)cg;
        if (key < best) best = key;
      }
#pragma unroll
      for (int off = 1; off <= 8; off <<= 1) {
        ull o = shflx64(best, off);
        if (o < best) best = o;
      }
      if (lr == 0) atomicMin(&keys[rg], best);
    }
  }
}

// ---------- outputs: quantized, full one-hot rows, loss via atomicAdd ----------
__global__ __launch_bounds__(256) void quantize_out(
    const float* __restrict__ z, const float* __restrict__ cb,
    const ull* __restrict__ keys, float* __restrict__ out) {
  __shared__ float ls[4];
  const int wid = threadIdx.x >> 6, lane = threadIdx.x & 63;
  const int row = blockIdx.x * 4 + wid;
  const int idx = (int)(keys[row] & 0xffffffffull);
  const float4 zv = *(const float4*)(z + (size_t)row * DIM + lane * 4);
  const float4 qv = *(const float4*)(cb + (size_t)idx * DIM + lane * 4);
  const float dx = __fsub_rn(qv.x, zv.x);
  const float dy = __fsub_rn(qv.y, zv.y);
  const float dzz = __fsub_rn(qv.z, zv.z);
  const float dw = __fsub_rn(qv.w, zv.w);
  float4 ov;
  ov.x = __fadd_rn(zv.x, dx); ov.y = __fadd_rn(zv.y, dy);
  ov.z = __fadd_rn(zv.z, dzz); ov.w = __fadd_rn(zv.w, dw);
  *(float4*)(out + (size_t)row * DIM + lane * 4) = ov;
  float s = dx * dx + dy * dy + dzz * dzz + dw * dw;
#pragma unroll
  for (int o = 32; o > 0; o >>= 1) s += __shfl_down(s, o);
  if (lane == 0) ls[wid] = s;

  // full one-hot row (no separate memset)
  float4* enc4 = (float4*)(out + (size_t)OUT_QUANT + 1 + (size_t)row * K_CODES);
  const int target = idx >> 2, comp = idx & 3;
#pragma unroll
  for (int i = 0; i < 4; ++i) {
    const int f4i = lane + 64 * i;
    float4 v = {0.f, 0.f, 0.f, 0.f};
    if (f4i == target) ((float*)&v)[comp] = 1.0f;
    enc4[f4i] = v;
  }

  __syncthreads();
  if (threadIdx.x == 0)
    atomicAdd(out + OUT_QUANT, (ls[0] + ls[1] + ls[2] + ls[3]) * (1.25f / 8388608.0f));
}

extern "C" void kernel_launch(void* const* d_in, const int* in_sizes, int n_in,
                              void* d_out, int out_size, void* d_ws, size_t ws_size,
                              hipStream_t stream) {
  const float* z = (const float*)d_in[0];
  const float* cb = (const float*)d_in[1];
  float* out = (float*)d_out;

  // ws: keys u64[32768] @0 | rn @256K | cn @384K | Ap @512K (48MB) | Bp @512K+48M (1.5MB)
  char* w = (char*)d_ws;
  ull* keys = (ull*)w;
  float* rn = (float*)(w + (256u << 10));
  float* cn = (float*)(w + (384u << 10));
  f16* Ap = (f16*)(w + (512u << 10));
  f16* Bp = (f16*)(w + (512u << 10) + (48u << 20));

  prep<<<NB_ZSPLIT + NB_ZNORM + NB_CSPLIT + NB_CNORM, 256, 0, stream>>>(
      z, cb, Ap, Bp, rn, cn, keys, out);
  gemm_argmin_f16<<<2048, 256, 0, stream>>>(Ap, Bp, rn, cn, keys);
  quantize_out<<<N_ROWS / 4, 256, 0, stream>>>(z, cb, keys, out);
}